// Round 20
// baseline (413.422 us; speedup 1.0000x reference)
//
#include <hip/hip_runtime.h>

#define N_   128
#define C_   12
#define L_   2048
#define H_   32
#define K_   8
#define CP_  6
#define KW_  9
#define FEAT_ 8192   // D*DIV*2*H*K

// Padded series in s_conv[3072]; pad = 4*DIL zeros in front, zeros after.
// Tap w of position q sits at padded index q + w*DIL - ... folded: q+p+w*DIL.
template<int DIL, bool GUARD>
__device__ __forceinline__ void conv_phase(const float* __restrict__ s,
                                           const float* __restrict__ wr,
                                           float* __restrict__ cx,
                                           int* __restrict__ cn,
                                           const int lane, const int wid)
{
    if constexpr (DIL == 1) {
        // 8 groups of 256 positions; wave w owns groups 4w..4w+3
        #pragma unroll
        for (int gg = 0; gg < 4; ++gg) {
            const int g = wid * 4 + gg;
            const int t = g * 256 + 4 * lane;
            float win[12];
            #pragma unroll
            for (int q = 0; q < 3; ++q) {
                const float4 v = *(const float4*)(s + t + 4 * q);  // ds_read_b128
                win[4*q+0] = v.x; win[4*q+1] = v.y;
                win[4*q+2] = v.z; win[4*q+3] = v.w;
            }
            #pragma unroll
            for (int p = 0; p < 4; ++p) {
                if (GUARD && g == 7 && p == 3 && lane == 63) continue;  // pos 2047
                float a0 = 0.f, a1 = 0.f, a2 = 0.f, a3 = 0.f,
                      a4 = 0.f, a5 = 0.f, a6 = 0.f, a7 = 0.f;
                #pragma unroll
                for (int w = 0; w < KW_; ++w) {
                    const float v = win[p + w];
                    a0 = fmaf(v, wr[0 * KW_ + w], a0);
                    a1 = fmaf(v, wr[1 * KW_ + w], a1);
                    a2 = fmaf(v, wr[2 * KW_ + w], a2);
                    a3 = fmaf(v, wr[3 * KW_ + w], a3);
                    a4 = fmaf(v, wr[4 * KW_ + w], a4);
                    a5 = fmaf(v, wr[5 * KW_ + w], a5);
                    a6 = fmaf(v, wr[6 * KW_ + w], a6);
                    a7 = fmaf(v, wr[7 * KW_ + w], a7);
                }
                const float mxa = fmaxf(fmaxf(a0, a1), a2);
                const float mxb = fmaxf(fmaxf(a3, a4), a5);
                const float mxc = fmaxf(fmaxf(a6, a7), mxa);
                const float mx  = fmaxf(mxb, mxc);
                const float mna = fminf(fminf(a0, a1), a2);
                const float mnb = fminf(fminf(a3, a4), a5);
                const float mnc = fminf(fminf(a6, a7), mna);
                const float mn  = fminf(mnb, mnc);
                cx[0] += (a0 == mx) ? a0 : 0.f;  cn[0] += (a0 == mn);
                cx[1] += (a1 == mx) ? a1 : 0.f;  cn[1] += (a1 == mn);
                cx[2] += (a2 == mx) ? a2 : 0.f;  cn[2] += (a2 == mn);
                cx[3] += (a3 == mx) ? a3 : 0.f;  cn[3] += (a3 == mn);
                cx[4] += (a4 == mx) ? a4 : 0.f;  cn[4] += (a4 == mn);
                cx[5] += (a5 == mx) ? a5 : 0.f;  cn[5] += (a5 == mn);
                cx[6] += (a6 == mx) ? a6 : 0.f;  cn[6] += (a6 == mn);
                cx[7] += (a7 == mx) ? a7 : 0.f;  cn[7] += (a7 == mn);
            }
        }
    } else {
        // 16 groups of 128 positions; wave w owns groups 8w..8w+7
        #pragma unroll 4
        for (int gg = 0; gg < 8; ++gg) {
            const int g = wid * 8 + gg;
            const int t = g * 128 + 2 * lane;
            float2 wv[9];
            #pragma unroll
            for (int w = 0; w < KW_; ++w)
                wv[w] = *(const float2*)(s + t + w * DIL);   // ds_read_b64
            #pragma unroll
            for (int p = 0; p < 2; ++p) {
                if (GUARD && g == 15 && p == 1 && lane == 63) continue;  // pos 2047
                float a0 = 0.f, a1 = 0.f, a2 = 0.f, a3 = 0.f,
                      a4 = 0.f, a5 = 0.f, a6 = 0.f, a7 = 0.f;
                #pragma unroll
                for (int w = 0; w < KW_; ++w) {
                    const float v = p ? wv[w].y : wv[w].x;
                    a0 = fmaf(v, wr[0 * KW_ + w], a0);
                    a1 = fmaf(v, wr[1 * KW_ + w], a1);
                    a2 = fmaf(v, wr[2 * KW_ + w], a2);
                    a3 = fmaf(v, wr[3 * KW_ + w], a3);
                    a4 = fmaf(v, wr[4 * KW_ + w], a4);
                    a5 = fmaf(v, wr[5 * KW_ + w], a5);
                    a6 = fmaf(v, wr[6 * KW_ + w], a6);
                    a7 = fmaf(v, wr[7 * KW_ + w], a7);
                }
                const float mxa = fmaxf(fmaxf(a0, a1), a2);
                const float mxb = fmaxf(fmaxf(a3, a4), a5);
                const float mxc = fmaxf(fmaxf(a6, a7), mxa);
                const float mx  = fmaxf(mxb, mxc);
                const float mna = fminf(fminf(a0, a1), a2);
                const float mnb = fminf(fminf(a3, a4), a5);
                const float mnc = fminf(fminf(a6, a7), mna);
                const float mn  = fminf(mnb, mnc);
                cx[0] += (a0 == mx) ? a0 : 0.f;  cn[0] += (a0 == mn);
                cx[1] += (a1 == mx) ? a1 : 0.f;  cn[1] += (a1 == mn);
                cx[2] += (a2 == mx) ? a2 : 0.f;  cn[2] += (a2 == mn);
                cx[3] += (a3 == mx) ? a3 : 0.f;  cn[3] += (a3 == mn);
                cx[4] += (a4 == mx) ? a4 : 0.f;  cn[4] += (a4 == mn);
                cx[5] += (a5 == mx) ? a5 : 0.f;  cn[5] += (a5 == mn);
                cx[6] += (a6 == mx) ? a6 : 0.f;  cn[6] += (a6 == mn);
                cx[7] += (a7 == mx) ? a7 : 0.f;  cn[7] += (a7 == mn);
            }
        }
    }
}

// 2 waves COOPERATE on one (n,comb,h): each stages/convs half. Tests the
// WG-slot-cap model (~10 WGs/CU regardless of size): 2 waves/WG -> ~20
// waves/CU. In-register df=1 diff keeps it at 2 barriers total.
__global__ __launch_bounds__(128, 4) void hydra_kernel(
    const float* __restrict__ X,   // [N, C, L]
    const float* __restrict__ W,   // [D, DIV, K*H, 1, KW]
    const int*   __restrict__ I,   // [D, DIV, H, CP]
    float* __restrict__ out)       // [N, FEAT]
{
    __shared__ __align__(16) float s_conv[3072];
    __shared__ float s_red[32];

    const int wid  = threadIdx.x >> 6;     // wave 0/1
    const int lane = threadIdx.x & 63;

    const int b_raw = blockIdx.x;          // 0..65535
    const int xcd   = b_raw & 7;
    const int sub   = b_raw >> 3;          // 0..8191
    const int n     = xcd * 16 + (sub >> 9);
    const int rem   = sub & 511;
    const int comb  = rem & 15;            // di*2 + df (low bits: I$ locality)
    const int h     = rem >> 4;

    const int df   = comb & 1;
    const int di   = comb >> 1;
    const int d    = 1 << di;
    const int Lsrc = L_ - df;              // 2048 or 2047
    const int pad  = 4 * d;

    // ---- zero pad + tail regions (covered by barrier 1) ----
    for (int j = threadIdx.x; j < pad; j += 128)               s_conv[j] = 0.0f;
    for (int j = pad + Lsrc + threadIdx.x; j < 3072; j += 128) s_conv[j] = 0.0f;

    // wave-uniform channel indices / weights
    const int* Ib = I + (comb * H_ + h) * CP_;
    const int c0 = Ib[0], c1 = Ib[1], c2 = Ib[2],
              c3 = Ib[3], c4 = Ib[4], c5 = Ib[5];
    const float* Xn = X + (size_t)n * (C_ * L_);
    const float* xp0 = Xn + c0 * L_;
    const float* xp1 = Xn + c1 * L_;
    const float* xp2 = Xn + c2 * L_;
    const float* xp3 = Xn + c3 * L_;
    const float* xp4 = Xn + c4 * L_;
    const float* xp5 = Xn + c5 * L_;

    const float* Wb = W + (size_t)(comb * (K_ * H_) + h * K_) * KW_;
    float wr[K_ * KW_];
    #pragma unroll
    for (int q = 0; q < K_ * KW_; ++q) wr[q] = Wb[q];

    // ---- staging: wave w owns t in [1024w, 1024w+1024); 4 bursts of 24 loads ----
    const int base = 1024 * wid;
    float sl[16];
    #pragma unroll
    for (int c = 0; c < 4; ++c) {
        float l0[4], l1[4], l2[4], l3[4], l4[4], l5[4];
        #pragma unroll
        for (int j = 0; j < 4; ++j) {
            const int t = base + c * 256 + j * 64 + lane;
            l0[j] = xp0[t]; l1[j] = xp1[t]; l2[j] = xp2[t];
            l3[j] = xp3[t]; l4[j] = xp4[t]; l5[j] = xp5[t];
        }
        #pragma unroll
        for (int j = 0; j < 4; ++j)
            sl[c * 4 + j] = ((l0[j] + l1[j]) + (l2[j] + l3[j])) + (l4[j] + l5[j]);
    }

    if (df == 0) {
        #pragma unroll
        for (int jj = 0; jj < 16; ++jj)
            s_conv[pad + base + jj * 64 + lane] = sl[jj];
    } else {
        // in-register diff: D[t] = S[t+1] - S[t]. S[t+1] via rotate-by-1 within
        // the chunk + broadcast of next chunk's lane0; one extra element at
        // base+1024 (wave0: real; wave1: dead, clamped).
        const int tx  = base + 1024;
        const int txc = (tx < 2048) ? tx : 2047;
        const float sx = ((xp0[txc] + xp1[txc]) + (xp2[txc] + xp3[txc]))
                       + (xp4[txc] + xp5[txc]);
        #pragma unroll
        for (int jj = 0; jj < 16; ++jj) {
            const float rot = __shfl_down(sl[jj], 1, 64);
            const float bc  = (jj < 15) ? __shfl(sl[jj + 1], 0, 64) : sx;
            const float nxt = (lane == 63) ? bc : rot;
            const int t = base + jj * 64 + lane;
            s_conv[pad + t] = (t == 2047) ? 0.0f : (nxt - sl[jj]);
        }
    }

    __syncthreads();   // barrier 1: pad zeros + full series visible

    // ---- conv + equality-scatter (wave-split groups) ----
    float cx[K_] = {0.f, 0.f, 0.f, 0.f, 0.f, 0.f, 0.f, 0.f};
    int   cn[K_] = {0, 0, 0, 0, 0, 0, 0, 0};

    switch (comb) {
        case  0: conv_phase<  1, false>(s_conv, wr, cx, cn, lane, wid); break;
        case  1: conv_phase<  1, true >(s_conv, wr, cx, cn, lane, wid); break;
        case  2: conv_phase<  2, false>(s_conv, wr, cx, cn, lane, wid); break;
        case  3: conv_phase<  2, true >(s_conv, wr, cx, cn, lane, wid); break;
        case  4: conv_phase<  4, false>(s_conv, wr, cx, cn, lane, wid); break;
        case  5: conv_phase<  4, true >(s_conv, wr, cx, cn, lane, wid); break;
        case  6: conv_phase<  8, false>(s_conv, wr, cx, cn, lane, wid); break;
        case  7: conv_phase<  8, true >(s_conv, wr, cx, cn, lane, wid); break;
        case  8: conv_phase< 16, false>(s_conv, wr, cx, cn, lane, wid); break;
        case  9: conv_phase< 16, true >(s_conv, wr, cx, cn, lane, wid); break;
        case 10: conv_phase< 32, false>(s_conv, wr, cx, cn, lane, wid); break;
        case 11: conv_phase< 32, true >(s_conv, wr, cx, cn, lane, wid); break;
        case 12: conv_phase< 64, false>(s_conv, wr, cx, cn, lane, wid); break;
        case 13: conv_phase< 64, true >(s_conv, wr, cx, cn, lane, wid); break;
        case 14: conv_phase<128, false>(s_conv, wr, cx, cn, lane, wid); break;
        default: conv_phase<128, true >(s_conv, wr, cx, cn, lane, wid); break;
    }

    // ---- per-wave butterfly, then tiny LDS combine across the 2 waves ----
    float red[16];
    #pragma unroll
    for (int k = 0; k < K_; ++k) { red[k] = cx[k]; red[8 + k] = (float)cn[k]; }
    #pragma unroll
    for (int off = 1; off < 64; off <<= 1) {
        #pragma unroll
        for (int q = 0; q < 16; ++q)
            red[q] += __shfl_xor(red[q], off, 64);
    }
    if (lane == 0) {
        #pragma unroll
        for (int q = 0; q < 16; ++q) s_red[wid * 16 + q] = red[q];
    }
    __syncthreads();   // barrier 2

    if (threadIdx.x < 16) {
        const int s = threadIdx.x >> 3;    // 0 = cmax, 1 = cmin
        const int k = threadIdx.x & 7;
        out[(size_t)n * FEAT_ + (comb * 2 + s) * (H_ * K_) + h * K_ + k] =
            s_red[threadIdx.x] + s_red[16 + threadIdx.x];
    }
}

extern "C" void kernel_launch(void* const* d_in, const int* in_sizes, int n_in,
                              void* d_out, int out_size, void* d_ws, size_t ws_size,
                              hipStream_t stream) {
    const float* X = (const float*)d_in[0];
    const float* W = (const float*)d_in[1];
    const int*   I = (const int*)d_in[2];
    float* out = (float*)d_out;

    const int blocks = N_ * 16 * H_;   // 65536: one (n,comb,h) per 2-wave block
    hipLaunchKernelGGL(hydra_kernel, dim3(blocks), dim3(128), 0, stream,
                       X, W, I, out);
}